// Round 7
// baseline (252.429 us; speedup 1.0000x reference)
//
#include <hip/hip_runtime.h>

// Tensor-ring FFN on MI355X — single-f16-product MFMA (fp32 acc).
// Round 7 = Round-6 (proven) + (a) SK=8 split-K on z-GEMMs with f16 partials
// (768-block grids, same ws byte footprint), (b) dead low-half writes deleted
// (xl/BT*l/ul). trgemm body/geometry byte-identical to validated R6.

typedef _Float16 f16;
typedef f16 f16x8 __attribute__((ext_vector_type(8)));
typedef f16 f16x4 __attribute__((ext_vector_type(4)));
typedef float f32x4 __attribute__((ext_vector_type(4)));

__device__ __forceinline__ void gload16(const void* g, void* l) {
    __builtin_amdgcn_global_load_lds(
        (const __attribute__((address_space(1))) void*)g,
        (__attribute__((address_space(3))) void*)l, 16, 0, 0);
}

// ---------------- chain: per-(chain,l) block computes M(l) = G1[i1]..G5[i5]@C3[i6]
__global__ void build_chain2_kernel(const float* __restrict__ a5, const float* __restrict__ a3,
                                    const float* __restrict__ b5, const float* __restrict__ b3,
                                    float* __restrict__ Pout, float* __restrict__ Qout) {
    __shared__ float Ma[256], Mb[256];
    const int l = blockIdx.x % 96, chain = blockIdx.x / 96;
    const float* G5 = chain ? b5 : a5;
    const float* G3 = chain ? b3 : a3;
    float* out = chain ? Qout : Pout;
    const int i6 = l % 3, lh = l / 3;
    const int dig[5] = {(lh >> 4) & 1, (lh >> 3) & 1, (lh >> 2) & 1, (lh >> 1) & 1, lh & 1};
    const int a = threadIdx.x >> 4, bn = threadIdx.x & 15;
    Ma[threadIdx.x] = G5[a * 32 + dig[0] * 16 + bn];
    __syncthreads();
    float* cur = Ma; float* nxt = Mb;
    for (int g = 1; g < 5; ++g) {
        float s = 0.f;
        #pragma unroll
        for (int r = 0; r < 16; ++r)
            s += cur[a * 16 + r] * G5[g * 512 + r * 32 + dig[g] * 16 + bn];
        nxt[threadIdx.x] = s;
        __syncthreads();
        float* t = cur; cur = nxt; nxt = t;
    }
    float s = 0.f;
    #pragma unroll
    for (int r = 0; r < 16; ++r)
        s += cur[a * 16 + r] * G3[r * 48 + i6 * 16 + bn];
    out[(a * 96 + l) * 16 + bn] = s;
}

// ---- B^T builders (f16 high half only) ----
__device__ __forceinline__ void permM_body(const float* __restrict__ in, f16* __restrict__ bh,
                                           int K, int q, int k0, float* t) {
    const float* src = in + ((size_t)q * K + k0) * 16;
    for (int i = threadIdx.x; i < 1024; i += 256)
        ((float4*)t)[i] = ((const float4*)src)[i];       // t[k_local*16 + j]
    __syncthreads();
    const int j = threadIdx.x >> 4, kc = (threadIdx.x & 15) * 16;
    f16* dh = bh + (size_t)(q * 16 + j) * K + k0 + kc;
    f16 vh[16];
    #pragma unroll
    for (int i = 0; i < 16; ++i) vh[i] = (f16)t[(kc + i) * 16 + j];
    *(f16x8*)(dh) = *(f16x8*)&vh[0]; *(f16x8*)(dh + 8) = *(f16x8*)&vh[8];
}
__device__ __forceinline__ void permO_body(const float* __restrict__ in, f16* __restrict__ bh,
                                           int N, int blk) {
    const int idx = blk * 256 + threadIdx.x;
    const int n = idx >> 8, k = idx & 255;
    bh[idx] = (f16)in[((k >> 4) * N + n) * 16 + (k & 15)];
}
__global__ void prep_bt_kernel(const float* __restrict__ c1_ind, const float* __restrict__ c1_off,
                               const float* __restrict__ c2_iff, const float* __restrict__ c2_outd,
                               f16* BT1h, f16* BT2h, f16* BT3h, f16* BT4h) {
    __shared__ float t[4096];
    int b = blockIdx.x;
    if (b < 32)   { permM_body(c1_ind, BT1h, 512,  b & 15, (b >> 4) * 256, t); return; }
    b -= 32;
    if (b < 128)  { permM_body(c2_iff, BT3h, 2048, b & 15, (b >> 4) * 256, t); return; }
    b -= 128;
    if (b < 2048) { permO_body(c1_off, BT2h, 2048, b); return; }
    b -= 2048;
    permO_body(c2_outd, BT4h, 512, b);
}

// ---- x -> f16 ----
__global__ void xsplit_kernel(const float* __restrict__ x, f16* __restrict__ xh) {
    const int idx = blockIdx.x * 256 + threadIdx.x;
    const float4 v = ((const float4*)x)[idx];
    f16x4 hh;
    hh[0] = (f16)v.x; hh[1] = (f16)v.y; hh[2] = (f16)v.z; hh[3] = (f16)v.w;
    ((f16x4*)xh)[idx] = hh;
}

// ---- ring fold over f16 split-K partials: grid (64 b, 6 lc), SK slices ----
__global__ void sfold_kernel(const f16* __restrict__ z, const float* __restrict__ P,
                             float* __restrict__ spart, int SK) {
    __shared__ f16 zs[4096];     // [l16][256] f16 (8 KB)
    __shared__ float Ps[4096];   // [(l*16+r)*16 + r0]
    const int b = blockIdx.x, lc = blockIdx.y, tid = threadIdx.x;
    const int r0 = tid >> 4, rE = tid & 15;
    for (int i = tid; i < 4096; i += 256) {
        const int rp = i & 15, r = (i >> 4) & 15, l = i >> 8;
        Ps[i] = P[((size_t)rp * 96 + lc * 16 + l) * 16 + r];
    }
    float acc = 0.f;
    for (int sk = 0; sk < SK; ++sk) {
        const f16x8* zsrc = (const f16x8*)(z + ((size_t)sk * 6144 + b * 96 + lc * 16) * 256);
        __syncthreads();
        for (int i = tid; i < 512; i += 256) ((f16x8*)zs)[i] = zsrc[i];
        __syncthreads();
        #pragma unroll
        for (int l = 0; l < 16; ++l)
            #pragma unroll
            for (int r = 0; r < 16; ++r)
                acc += (float)zs[l * 256 + r * 16 + rE] * Ps[(l * 16 + r) * 16 + r0];
    }
    spart[((size_t)lc * 64 + b) * 256 + tid] = acc;
}

// ---- expand: u[(b*96+o1)*256 + tid] -> f16 ----
__global__ void uexpand_kernel(const float* __restrict__ spart, const float* __restrict__ O,
                               f16* __restrict__ uh) {
    __shared__ float s_sh[256], o_sh[256];
    const int o1 = blockIdx.x, b = blockIdx.y, tid = threadIdx.x;
    float sv = 0.f;
    #pragma unroll
    for (int lc = 0; lc < 6; ++lc) sv += spart[((size_t)lc * 64 + b) * 256 + tid];
    s_sh[tid] = sv;
    o_sh[tid] = O[((tid >> 4) * 96 + o1) * 16 + (tid & 15)];
    __syncthreads();
    const int dd = tid >> 4, a = tid & 15;
    float acc = 0.f;
    #pragma unroll
    for (int c = 0; c < 16; ++c) acc += s_sh[a * 16 + c] * o_sh[c * 16 + dd];
    uh[((size_t)b * 96 + o1) * 256 + tid] = (f16)acc;
}

// ---- single-f16 MFMA GEMM, m97 structure (validated R6 body) ----
// 128x128 tile, BK=64, 4 waves (2x2), wave-tile 64x64, global_load_lds staging.
// LDS: [region 0..7][ks 0..1][lane 0..63][8 f16]; 32 KB -> 4 blocks/CU.
// EPI 0: Czh[bz][M][N] = (f16)v (split-K partial, f16);
// EPI 1: +bias, relu -> Ch; EPI 2: +bias -> Cf (fp32).
template<int EPI>
__global__ __launch_bounds__(256, 4) void trgemm_kernel(
    const f16* __restrict__ Ah, const f16* __restrict__ BTh,
    const float* __restrict__ bias,
    float* __restrict__ Cf, f16* __restrict__ Ch,
    int M, int N, int K, int kchunk)
{
    __shared__ f16 As[8192];
    __shared__ f16 Bs[8192];
    const int n0 = blockIdx.x * 128, m0 = blockIdx.y * 128;
    const int kbase = blockIdx.z * kchunk;
    const int tid = threadIdx.x;
    const int w = tid >> 6, lane = tid & 63;
    const int wm = w >> 1, wn = w & 1;
    const int lr = lane & 15, lq = lane >> 4;

    // staging: wave w stages regions {2w, 2w+1} of both A and B
    const int ra = 2 * w;
    size_t aoff0 = (size_t)(m0 + ra * 16 + lr) * K + kbase + lq * 8;
    size_t aoff1 = aoff0 + (size_t)16 * K;
    size_t boff0 = (size_t)(n0 + ra * 16 + lr) * K + kbase + lq * 8;
    size_t boff1 = boff0 + (size_t)16 * K;

    f32x4 acc[4][4];
    #pragma unroll
    for (int i = 0; i < 4; ++i)
        #pragma unroll
        for (int j = 0; j < 4; ++j) acc[i][j] = (f32x4)0.f;

    const int nkt = kchunk >> 6;
    for (int kt = 0; kt < nkt; ++kt) {
        __syncthreads();   // all waves done reading previous tile
        #pragma unroll
        for (int c = 0; c < 2; ++c) {
            gload16(Ah + aoff0 + c * 32, &As[(ra + 0) * 1024 + c * 512]);
            gload16(Ah + aoff1 + c * 32, &As[(ra + 1) * 1024 + c * 512]);
            gload16(BTh + boff0 + c * 32, &Bs[(ra + 0) * 1024 + c * 512]);
            gload16(BTh + boff1 + c * 32, &Bs[(ra + 1) * 1024 + c * 512]);
        }
        aoff0 += 64; aoff1 += 64; boff0 += 64; boff1 += 64;
        __syncthreads();   // compiler drains vmcnt before barrier -> tile landed
        #pragma unroll
        for (int ks = 0; ks < 2; ++ks) {
            f16x8 afh[4], bfh[4];
            #pragma unroll
            for (int mf = 0; mf < 4; ++mf)
                afh[mf] = *(const f16x8*)&As[(wm * 4 + mf) * 1024 + ks * 512 + lane * 8];
            #pragma unroll
            for (int nf = 0; nf < 4; ++nf)
                bfh[nf] = *(const f16x8*)&Bs[(wn * 4 + nf) * 1024 + ks * 512 + lane * 8];
            #pragma unroll
            for (int mf = 0; mf < 4; ++mf)
                #pragma unroll
                for (int nf = 0; nf < 4; ++nf)
                    acc[mf][nf] = __builtin_amdgcn_mfma_f32_16x16x32_f16(afh[mf], bfh[nf], acc[mf][nf], 0, 0, 0);
        }
    }

    #pragma unroll
    for (int mf = 0; mf < 4; ++mf)
        #pragma unroll
        for (int nf = 0; nf < 4; ++nf)
            #pragma unroll
            for (int r = 0; r < 4; ++r) {
                const int row = m0 + wm * 64 + mf * 16 + lq * 4 + r;
                const int col = n0 + wn * 64 + nf * 16 + lr;
                float v = acc[mf][nf][r];
                if constexpr (EPI == 0) {
                    Ch[((size_t)blockIdx.z * M + row) * N + col] = (f16)v;
                } else {
                    v += bias[(size_t)(row % 96) * N + col];
                    if constexpr (EPI == 1) {
                        v = fmaxf(v, 0.f);
                        Ch[(size_t)row * N + col] = (f16)v;
                    } else {
                        Cf[(size_t)row * N + col] = v;
                    }
                }
            }
}

extern "C" void kernel_launch(void* const* d_in, const int* in_sizes, int n_in,
                              void* d_out, int out_size, void* d_ws, size_t ws_size,
                              hipStream_t stream) {
    const float* x        = (const float*)d_in[0];
    const float* c1_in2   = (const float*)d_in[1];
    const float* c1_in3   = (const float*)d_in[2];
    const float* c1_ind   = (const float*)d_in[3];
    const float* c1_oseq  = (const float*)d_in[4];
    const float* c1_off   = (const float*)d_in[5];
    const float* b1       = (const float*)d_in[6];
    const float* c2_iseq  = (const float*)d_in[7];
    const float* c2_iff   = (const float*)d_in[8];
    const float* c2_out2  = (const float*)d_in[9];
    const float* c2_out3  = (const float*)d_in[10];
    const float* c2_outd  = (const float*)d_in[11];
    const float* b2       = (const float*)d_in[12];
    float* out = (float*)d_out;

    // ---- workspace layout: byte-identical offsets to proven R4/R6 ----
    char* base = (char*)d_ws;
    float* Pseq1 = (float*)base;                       // 24576 f
    float* Qseq2 = (float*)(base + 98304);             // 24576 f
    f16*   BT1h  = (f16*)(base + 196608);              // 131072 (+dead l slot)
    f16*   BT2h  = BT1h + 2 * 131072;                  // 524288
    f16*   BT3h  = BT2h + 2 * 524288;                  // 524288
    f16*   BT4h  = BT3h + 2 * 524288;                  // 131072
    char*  hreg  = base + 5439488;                     // 50331648 B
    f16*   hh    = (f16*)hreg;                         // 12582912 f16
    f16*   xh    = (f16*)hreg;                         // alias (dies before h)
    float* spart = (float*)(hreg + 12582912);          // alias, 98304 f
    char*  zreg  = base + 55771136;                    // 25165824 B
    f16*   zp    = (f16*)zreg;                         // SK=8 x 1572864 f16
    f16*   uh    = (f16*)zreg;                         // alias (zp dead at uexpand)

    const int SK = 8;   // f16 partials: same byte footprint as proven layout

    // prep
    build_chain2_kernel<<<192, 256, 0, stream>>>(c1_in2, c1_in3, c2_out2, c2_out3, Pseq1, Qseq2);
    prep_bt_kernel<<<2720, 256, 0, stream>>>(c1_ind, c1_off, c2_iff, c2_outd,
                                             BT1h, BT2h, BT3h, BT4h);
    xsplit_kernel<<<3072, 256, 0, stream>>>(x, xh);

    // layer 1
    trgemm_kernel<0><<<dim3(2, 48, SK), 256, 0, stream>>>(xh, BT1h, nullptr,
                                                          nullptr, zp, 6144, 256, 512, 512 / SK);
    sfold_kernel<<<dim3(64, 6), 256, 0, stream>>>(zp, Pseq1, spart, SK);
    uexpand_kernel<<<dim3(96, 64), 256, 0, stream>>>(spart, c1_oseq, uh);
    trgemm_kernel<1><<<dim3(16, 48, 1), 256, 0, stream>>>(uh, BT2h, b1,
                                                          nullptr, hh, 6144, 2048, 256, 256);
    // layer 2
    trgemm_kernel<0><<<dim3(2, 48, SK), 256, 0, stream>>>(hh, BT3h, nullptr,
                                                          nullptr, zp, 6144, 256, 2048, 2048 / SK);
    sfold_kernel<<<dim3(64, 6), 256, 0, stream>>>(zp, c2_iseq, spart, SK);
    uexpand_kernel<<<dim3(96, 64), 256, 0, stream>>>(spart, Qseq2, uh);
    trgemm_kernel<2><<<dim3(4, 48, 1), 256, 0, stream>>>(uh, BT4h, b2,
                                                         out, nullptr, 6144, 512, 256, 256);
}

// Round 8
// 245.030 us; speedup vs baseline: 1.0302x; 1.0302x over previous
//
#include <hip/hip_runtime.h>

// Tensor-ring FFN on MI355X — single-f16-product MFMA (fp32 acc).
// Round 8 = Round-7 + parallel fold: sfold one sk-slice per block (grid
// (64,6,SK)=3072 blocks), tiny sred reduce (48 slices -> sfin), uexpand reads
// sfin. GEMMs/prep/layout byte-identical to R7 (proven).

typedef _Float16 f16;
typedef f16 f16x8 __attribute__((ext_vector_type(8)));
typedef f16 f16x4 __attribute__((ext_vector_type(4)));
typedef float f32x4 __attribute__((ext_vector_type(4)));

__device__ __forceinline__ void gload16(const void* g, void* l) {
    __builtin_amdgcn_global_load_lds(
        (const __attribute__((address_space(1))) void*)g,
        (__attribute__((address_space(3))) void*)l, 16, 0, 0);
}

// ---------------- chain: per-(chain,l) block computes M(l) = G1[i1]..G5[i5]@C3[i6]
__global__ void build_chain2_kernel(const float* __restrict__ a5, const float* __restrict__ a3,
                                    const float* __restrict__ b5, const float* __restrict__ b3,
                                    float* __restrict__ Pout, float* __restrict__ Qout) {
    __shared__ float Ma[256], Mb[256];
    const int l = blockIdx.x % 96, chain = blockIdx.x / 96;
    const float* G5 = chain ? b5 : a5;
    const float* G3 = chain ? b3 : a3;
    float* out = chain ? Qout : Pout;
    const int i6 = l % 3, lh = l / 3;
    const int dig[5] = {(lh >> 4) & 1, (lh >> 3) & 1, (lh >> 2) & 1, (lh >> 1) & 1, lh & 1};
    const int a = threadIdx.x >> 4, bn = threadIdx.x & 15;
    Ma[threadIdx.x] = G5[a * 32 + dig[0] * 16 + bn];
    __syncthreads();
    float* cur = Ma; float* nxt = Mb;
    for (int g = 1; g < 5; ++g) {
        float s = 0.f;
        #pragma unroll
        for (int r = 0; r < 16; ++r)
            s += cur[a * 16 + r] * G5[g * 512 + r * 32 + dig[g] * 16 + bn];
        nxt[threadIdx.x] = s;
        __syncthreads();
        float* t = cur; cur = nxt; nxt = t;
    }
    float s = 0.f;
    #pragma unroll
    for (int r = 0; r < 16; ++r)
        s += cur[a * 16 + r] * G3[r * 48 + i6 * 16 + bn];
    out[(a * 96 + l) * 16 + bn] = s;
}

// ---- B^T builders (f16 high half only) ----
__device__ __forceinline__ void permM_body(const float* __restrict__ in, f16* __restrict__ bh,
                                           int K, int q, int k0, float* t) {
    const float* src = in + ((size_t)q * K + k0) * 16;
    for (int i = threadIdx.x; i < 1024; i += 256)
        ((float4*)t)[i] = ((const float4*)src)[i];       // t[k_local*16 + j]
    __syncthreads();
    const int j = threadIdx.x >> 4, kc = (threadIdx.x & 15) * 16;
    f16* dh = bh + (size_t)(q * 16 + j) * K + k0 + kc;
    f16 vh[16];
    #pragma unroll
    for (int i = 0; i < 16; ++i) vh[i] = (f16)t[(kc + i) * 16 + j];
    *(f16x8*)(dh) = *(f16x8*)&vh[0]; *(f16x8*)(dh + 8) = *(f16x8*)&vh[8];
}
__device__ __forceinline__ void permO_body(const float* __restrict__ in, f16* __restrict__ bh,
                                           int N, int blk) {
    const int idx = blk * 256 + threadIdx.x;
    const int n = idx >> 8, k = idx & 255;
    bh[idx] = (f16)in[((k >> 4) * N + n) * 16 + (k & 15)];
}
__global__ void prep_bt_kernel(const float* __restrict__ c1_ind, const float* __restrict__ c1_off,
                               const float* __restrict__ c2_iff, const float* __restrict__ c2_outd,
                               f16* BT1h, f16* BT2h, f16* BT3h, f16* BT4h) {
    __shared__ float t[4096];
    int b = blockIdx.x;
    if (b < 32)   { permM_body(c1_ind, BT1h, 512,  b & 15, (b >> 4) * 256, t); return; }
    b -= 32;
    if (b < 128)  { permM_body(c2_iff, BT3h, 2048, b & 15, (b >> 4) * 256, t); return; }
    b -= 128;
    if (b < 2048) { permO_body(c1_off, BT2h, 2048, b); return; }
    b -= 2048;
    permO_body(c2_outd, BT4h, 512, b);
}

// ---- x -> f16 ----
__global__ void xsplit_kernel(const float* __restrict__ x, f16* __restrict__ xh) {
    const int idx = blockIdx.x * 256 + threadIdx.x;
    const float4 v = ((const float4*)x)[idx];
    f16x4 hh;
    hh[0] = (f16)v.x; hh[1] = (f16)v.y; hh[2] = (f16)v.z; hh[3] = (f16)v.w;
    ((f16x4*)xh)[idx] = hh;
}

// ---- ring fold, one sk-slice per block: grid (64 b, 6 lc, SK sk) ----
// spart2[(sk*6+lc)*64+b][256] = sum_{l in chunk, r} z[sk][b*96+l][r*16+rE]*P[r0,l,r]
__global__ void sfold_kernel(const f16* __restrict__ z, const float* __restrict__ P,
                             float* __restrict__ spart2) {
    __shared__ f16 zs[4096];     // [l16][256] f16 (8 KB)
    __shared__ float Ps[4096];   // [(l*16+r)*16 + r0]
    const int b = blockIdx.x, lc = blockIdx.y, sk = blockIdx.z, tid = threadIdx.x;
    const int r0 = tid >> 4, rE = tid & 15;
    for (int i = tid; i < 4096; i += 256) {
        const int rp = i & 15, r = (i >> 4) & 15, l = i >> 8;
        Ps[i] = P[((size_t)rp * 96 + lc * 16 + l) * 16 + r];
    }
    const f16x8* zsrc = (const f16x8*)(z + ((size_t)sk * 6144 + b * 96 + lc * 16) * 256);
    for (int i = tid; i < 512; i += 256) ((f16x8*)zs)[i] = zsrc[i];
    __syncthreads();
    float acc = 0.f;
    #pragma unroll
    for (int l = 0; l < 16; ++l)
        #pragma unroll
        for (int r = 0; r < 16; ++r)
            acc += (float)zs[l * 256 + r * 16 + rE] * Ps[(l * 16 + r) * 16 + r0];
    spart2[(((size_t)sk * 6 + lc) * 64 + b) * 256 + tid] = acc;
}

// ---- reduce 48 slices -> sfin[64][256] ----
__global__ void sred_kernel(const float* __restrict__ spart2, float* __restrict__ sfin,
                            int nsl) {
    const int b = blockIdx.x, tid = threadIdx.x;
    float acc = 0.f;
    #pragma unroll 8
    for (int s = 0; s < nsl; ++s) acc += spart2[((size_t)s * 64 + b) * 256 + tid];
    sfin[b * 256 + tid] = acc;
}

// ---- expand: u[(b*96+o1)*256 + tid] -> f16 ----
__global__ void uexpand_kernel(const float* __restrict__ sfin, const float* __restrict__ O,
                               f16* __restrict__ uh) {
    __shared__ float s_sh[256], o_sh[256];
    const int o1 = blockIdx.x, b = blockIdx.y, tid = threadIdx.x;
    s_sh[tid] = sfin[b * 256 + tid];
    o_sh[tid] = O[((tid >> 4) * 96 + o1) * 16 + (tid & 15)];
    __syncthreads();
    const int dd = tid >> 4, a = tid & 15;
    float acc = 0.f;
    #pragma unroll
    for (int c = 0; c < 16; ++c) acc += s_sh[a * 16 + c] * o_sh[c * 16 + dd];
    uh[((size_t)b * 96 + o1) * 256 + tid] = (f16)acc;
}

// ---- single-f16 MFMA GEMM, m97 structure (validated R6/R7 body) ----
// 128x128 tile, BK=64, 4 waves (2x2), wave-tile 64x64, global_load_lds staging.
// LDS: [region 0..7][ks 0..1][lane 0..63][8 f16]; 32 KB -> 4 blocks/CU.
// EPI 0: Ch[bz][M][N] = (f16)v (split-K partial);
// EPI 1: +bias, relu -> Ch; EPI 2: +bias -> Cf (fp32).
template<int EPI>
__global__ __launch_bounds__(256, 4) void trgemm_kernel(
    const f16* __restrict__ Ah, const f16* __restrict__ BTh,
    const float* __restrict__ bias,
    float* __restrict__ Cf, f16* __restrict__ Ch,
    int M, int N, int K, int kchunk)
{
    __shared__ f16 As[8192];
    __shared__ f16 Bs[8192];
    const int n0 = blockIdx.x * 128, m0 = blockIdx.y * 128;
    const int kbase = blockIdx.z * kchunk;
    const int tid = threadIdx.x;
    const int w = tid >> 6, lane = tid & 63;
    const int wm = w >> 1, wn = w & 1;
    const int lr = lane & 15, lq = lane >> 4;

    // staging: wave w stages regions {2w, 2w+1} of both A and B
    const int ra = 2 * w;
    size_t aoff0 = (size_t)(m0 + ra * 16 + lr) * K + kbase + lq * 8;
    size_t aoff1 = aoff0 + (size_t)16 * K;
    size_t boff0 = (size_t)(n0 + ra * 16 + lr) * K + kbase + lq * 8;
    size_t boff1 = boff0 + (size_t)16 * K;

    f32x4 acc[4][4];
    #pragma unroll
    for (int i = 0; i < 4; ++i)
        #pragma unroll
        for (int j = 0; j < 4; ++j) acc[i][j] = (f32x4)0.f;

    const int nkt = kchunk >> 6;
    for (int kt = 0; kt < nkt; ++kt) {
        __syncthreads();   // all waves done reading previous tile
        #pragma unroll
        for (int c = 0; c < 2; ++c) {
            gload16(Ah + aoff0 + c * 32, &As[(ra + 0) * 1024 + c * 512]);
            gload16(Ah + aoff1 + c * 32, &As[(ra + 1) * 1024 + c * 512]);
            gload16(BTh + boff0 + c * 32, &Bs[(ra + 0) * 1024 + c * 512]);
            gload16(BTh + boff1 + c * 32, &Bs[(ra + 1) * 1024 + c * 512]);
        }
        aoff0 += 64; aoff1 += 64; boff0 += 64; boff1 += 64;
        __syncthreads();   // compiler drains vmcnt before barrier -> tile landed
        #pragma unroll
        for (int ks = 0; ks < 2; ++ks) {
            f16x8 afh[4], bfh[4];
            #pragma unroll
            for (int mf = 0; mf < 4; ++mf)
                afh[mf] = *(const f16x8*)&As[(wm * 4 + mf) * 1024 + ks * 512 + lane * 8];
            #pragma unroll
            for (int nf = 0; nf < 4; ++nf)
                bfh[nf] = *(const f16x8*)&Bs[(wn * 4 + nf) * 1024 + ks * 512 + lane * 8];
            #pragma unroll
            for (int mf = 0; mf < 4; ++mf)
                #pragma unroll
                for (int nf = 0; nf < 4; ++nf)
                    acc[mf][nf] = __builtin_amdgcn_mfma_f32_16x16x32_f16(afh[mf], bfh[nf], acc[mf][nf], 0, 0, 0);
        }
    }

    #pragma unroll
    for (int mf = 0; mf < 4; ++mf)
        #pragma unroll
        for (int nf = 0; nf < 4; ++nf)
            #pragma unroll
            for (int r = 0; r < 4; ++r) {
                const int row = m0 + wm * 64 + mf * 16 + lq * 4 + r;
                const int col = n0 + wn * 64 + nf * 16 + lr;
                float v = acc[mf][nf][r];
                if constexpr (EPI == 0) {
                    Ch[((size_t)blockIdx.z * M + row) * N + col] = (f16)v;
                } else {
                    v += bias[(size_t)(row % 96) * N + col];
                    if constexpr (EPI == 1) {
                        v = fmaxf(v, 0.f);
                        Ch[(size_t)row * N + col] = (f16)v;
                    } else {
                        Cf[(size_t)row * N + col] = v;
                    }
                }
            }
}

extern "C" void kernel_launch(void* const* d_in, const int* in_sizes, int n_in,
                              void* d_out, int out_size, void* d_ws, size_t ws_size,
                              hipStream_t stream) {
    const float* x        = (const float*)d_in[0];
    const float* c1_in2   = (const float*)d_in[1];
    const float* c1_in3   = (const float*)d_in[2];
    const float* c1_ind   = (const float*)d_in[3];
    const float* c1_oseq  = (const float*)d_in[4];
    const float* c1_off   = (const float*)d_in[5];
    const float* b1       = (const float*)d_in[6];
    const float* c2_iseq  = (const float*)d_in[7];
    const float* c2_iff   = (const float*)d_in[8];
    const float* c2_out2  = (const float*)d_in[9];
    const float* c2_out3  = (const float*)d_in[10];
    const float* c2_outd  = (const float*)d_in[11];
    const float* b2       = (const float*)d_in[12];
    float* out = (float*)d_out;

    // ---- workspace layout: byte-identical offsets to proven R7 ----
    char* base = (char*)d_ws;
    float* Pseq1 = (float*)base;                       // 24576 f
    float* Qseq2 = (float*)(base + 98304);             // 24576 f
    f16*   BT1h  = (f16*)(base + 196608);              // 131072 (+dead l slot)
    f16*   BT2h  = BT1h + 2 * 131072;                  // 524288
    f16*   BT3h  = BT2h + 2 * 524288;                  // 524288
    f16*   BT4h  = BT3h + 2 * 524288;                  // 131072
    char*  hreg  = base + 5439488;                     // 50331648 B
    f16*   hh    = (f16*)hreg;                         // 12582912 f16 (25165824 B)
    f16*   xh    = (f16*)hreg;                         // alias (dies before h)
    float* spart2= (float*)(hreg + 25165824);          // 48*64*256 f = 3145728 B (dead hl slot)
    float* sfin  = (float*)(hreg + 28311552);          // 16384 f = 65536 B
    char*  zreg  = base + 55771136;                    // 25165824 B
    f16*   zp    = (f16*)zreg;                         // SK=8 x 1572864 f16
    f16*   uh    = (f16*)zreg;                         // alias (zp dead at uexpand)

    const int SK = 8;

    // prep
    build_chain2_kernel<<<192, 256, 0, stream>>>(c1_in2, c1_in3, c2_out2, c2_out3, Pseq1, Qseq2);
    prep_bt_kernel<<<2720, 256, 0, stream>>>(c1_ind, c1_off, c2_iff, c2_outd,
                                             BT1h, BT2h, BT3h, BT4h);
    xsplit_kernel<<<3072, 256, 0, stream>>>(x, xh);

    // layer 1
    trgemm_kernel<0><<<dim3(2, 48, SK), 256, 0, stream>>>(xh, BT1h, nullptr,
                                                          nullptr, zp, 6144, 256, 512, 512 / SK);
    sfold_kernel<<<dim3(64, 6, SK), 256, 0, stream>>>(zp, Pseq1, spart2);
    sred_kernel<<<64, 256, 0, stream>>>(spart2, sfin, 6 * SK);
    uexpand_kernel<<<dim3(96, 64), 256, 0, stream>>>(sfin, c1_oseq, uh);
    trgemm_kernel<1><<<dim3(16, 48, 1), 256, 0, stream>>>(uh, BT2h, b1,
                                                          nullptr, hh, 6144, 2048, 256, 256);
    // layer 2
    trgemm_kernel<0><<<dim3(2, 48, SK), 256, 0, stream>>>(hh, BT3h, nullptr,
                                                          nullptr, zp, 6144, 256, 2048, 2048 / SK);
    sfold_kernel<<<dim3(64, 6, SK), 256, 0, stream>>>(zp, c2_iseq, spart2);
    sred_kernel<<<64, 256, 0, stream>>>(spart2, sfin, 6 * SK);
    uexpand_kernel<<<dim3(96, 64), 256, 0, stream>>>(sfin, Qseq2, uh);
    trgemm_kernel<2><<<dim3(4, 48, 1), 256, 0, stream>>>(uh, BT4h, b2,
                                                         out, nullptr, 6144, 512, 256, 256);
}

// Round 9
// 229.996 us; speedup vs baseline: 1.0975x; 1.0654x over previous
//
#include <hip/hip_runtime.h>

// Tensor-ring FFN on MI355X — single-f16-product MFMA (fp32 acc).
// Round 9 = Round-8 GEMMs (byte-identical, validated) + fold-subsystem fix:
//   (a) P2 layout [l][r][rp] for fold-P (coalesced Ps staging; R8's 800MB
//       scattered-gather L2 traffic was the sfold cost), c2_iseq repacked once;
//   (b) sred+uexpand fused into sexpand (grid 64x4, padded s_sh, coalesced O).
// Launches 13 -> 11.

typedef _Float16 f16;
typedef f16 f16x8 __attribute__((ext_vector_type(8)));
typedef f16 f16x4 __attribute__((ext_vector_type(4)));
typedef float f32x4 __attribute__((ext_vector_type(4)));

__device__ __forceinline__ void gload16(const void* g, void* l) {
    __builtin_amdgcn_global_load_lds(
        (const __attribute__((address_space(1))) void*)g,
        (__attribute__((address_space(3))) void*)l, 16, 0, 0);
}

// ---------------- chain + repack ----------------
// blocks [0,192): chain c=blk/96, l=blk%96 -> M(l) = G1..G5 @ C3
//   chain 0 (layer-1 fold P): store NEW layout P2[l*256 + r*16 + rp]
//   chain 1 (layer-2 expand O): store OLD layout Q[(rp*96+l)*16 + r]
// blocks [192,288): repack c2_iseq -> P2c[l*256 + r*16 + rp]
__global__ void build_chain2_kernel(const float* __restrict__ a5, const float* __restrict__ a3,
                                    const float* __restrict__ b5, const float* __restrict__ b3,
                                    const float* __restrict__ c2_iseq,
                                    float* __restrict__ Pout, float* __restrict__ Qout,
                                    float* __restrict__ P2c) {
    __shared__ float Ma[256], Mb[256];
    const int blk = blockIdx.x;
    const int a = threadIdx.x >> 4, bn = threadIdx.x & 15;
    if (blk >= 192) {   // repack c2_iseq into P2 layout
        const int l = blk - 192;
        P2c[l * 256 + bn * 16 + a] = c2_iseq[(a * 96 + l) * 16 + bn];
        return;
    }
    const int l = blk % 96, chain = blk / 96;
    const float* G5 = chain ? b5 : a5;
    const float* G3 = chain ? b3 : a3;
    const int i6 = l % 3, lh = l / 3;
    const int dig[5] = {(lh >> 4) & 1, (lh >> 3) & 1, (lh >> 2) & 1, (lh >> 1) & 1, lh & 1};
    Ma[threadIdx.x] = G5[a * 32 + dig[0] * 16 + bn];
    __syncthreads();
    float* cur = Ma; float* nxt = Mb;
    for (int g = 1; g < 5; ++g) {
        float s = 0.f;
        #pragma unroll
        for (int r = 0; r < 16; ++r)
            s += cur[a * 16 + r] * G5[g * 512 + r * 32 + dig[g] * 16 + bn];
        nxt[threadIdx.x] = s;
        __syncthreads();
        float* t = cur; cur = nxt; nxt = t;
    }
    float s = 0.f;
    #pragma unroll
    for (int r = 0; r < 16; ++r)
        s += cur[a * 16 + r] * G3[r * 48 + i6 * 16 + bn];
    if (chain == 0) Pout[l * 256 + bn * 16 + a] = s;       // P2 layout
    else            Qout[(a * 96 + l) * 16 + bn] = s;      // old layout (O)
}

// ---- B^T builders (f16 high half only) ----
__device__ __forceinline__ void permM_body(const float* __restrict__ in, f16* __restrict__ bh,
                                           int K, int q, int k0, float* t) {
    const float* src = in + ((size_t)q * K + k0) * 16;
    for (int i = threadIdx.x; i < 1024; i += 256)
        ((float4*)t)[i] = ((const float4*)src)[i];       // t[k_local*16 + j]
    __syncthreads();
    const int j = threadIdx.x >> 4, kc = (threadIdx.x & 15) * 16;
    f16* dh = bh + (size_t)(q * 16 + j) * K + k0 + kc;
    f16 vh[16];
    #pragma unroll
    for (int i = 0; i < 16; ++i) vh[i] = (f16)t[(kc + i) * 16 + j];
    *(f16x8*)(dh) = *(f16x8*)&vh[0]; *(f16x8*)(dh + 8) = *(f16x8*)&vh[8];
}
__device__ __forceinline__ void permO_body(const float* __restrict__ in, f16* __restrict__ bh,
                                           int N, int blk) {
    const int idx = blk * 256 + threadIdx.x;
    const int n = idx >> 8, k = idx & 255;
    bh[idx] = (f16)in[((k >> 4) * N + n) * 16 + (k & 15)];
}
__global__ void prep_bt_kernel(const float* __restrict__ c1_ind, const float* __restrict__ c1_off,
                               const float* __restrict__ c2_iff, const float* __restrict__ c2_outd,
                               f16* BT1h, f16* BT2h, f16* BT3h, f16* BT4h) {
    __shared__ float t[4096];
    int b = blockIdx.x;
    if (b < 32)   { permM_body(c1_ind, BT1h, 512,  b & 15, (b >> 4) * 256, t); return; }
    b -= 32;
    if (b < 128)  { permM_body(c2_iff, BT3h, 2048, b & 15, (b >> 4) * 256, t); return; }
    b -= 128;
    if (b < 2048) { permO_body(c1_off, BT2h, 2048, b); return; }
    b -= 2048;
    permO_body(c2_outd, BT4h, 512, b);
}

// ---- x -> f16 ----
__global__ void xsplit_kernel(const float* __restrict__ x, f16* __restrict__ xh) {
    const int idx = blockIdx.x * 256 + threadIdx.x;
    const float4 v = ((const float4*)x)[idx];
    f16x4 hh;
    hh[0] = (f16)v.x; hh[1] = (f16)v.y; hh[2] = (f16)v.z; hh[3] = (f16)v.w;
    ((f16x4*)xh)[idx] = hh;
}

// ---- ring fold, one sk-slice per block: grid (64 b, 6 lc, SK sk) ----
// P2 layout: P2[l*256 + r*16 + rp], contiguous 4096-float slice per lc.
__global__ void sfold_kernel(const f16* __restrict__ z, const float* __restrict__ P2,
                             float* __restrict__ spart2) {
    __shared__ f16 zs[4096];     // [l16][256] f16 (8 KB)
    __shared__ float Ps[4096];   // [(l*16+r)*16 + rp] (16 KB)
    const int b = blockIdx.x, lc = blockIdx.y, sk = blockIdx.z, tid = threadIdx.x;
    const int r0 = tid >> 4, rE = tid & 15;
    const float4* psrc = (const float4*)(P2 + lc * 4096);
    for (int i = tid; i < 1024; i += 256) ((float4*)Ps)[i] = psrc[i];   // coalesced
    const f16x8* zsrc = (const f16x8*)(z + ((size_t)sk * 6144 + b * 96 + lc * 16) * 256);
    for (int i = tid; i < 512; i += 256) ((f16x8*)zs)[i] = zsrc[i];
    __syncthreads();
    float acc = 0.f;
    #pragma unroll
    for (int l = 0; l < 16; ++l)
        #pragma unroll
        for (int r = 0; r < 16; ++r)
            acc += (float)zs[l * 256 + r * 16 + rE] * Ps[(l * 16 + r) * 16 + r0];
    spart2[(((size_t)sk * 6 + lc) * 64 + b) * 256 + tid] = acc;
}

// ---- fused reduce+expand: grid (64 b, 4 og), 24 o1 per block ----
// s_sh = sum of 48 partial slices (17-padded); u[(b*96+o1)*256+tid] -> f16
__global__ void sexpand_kernel(const float* __restrict__ spart2, const float* __restrict__ O,
                               f16* __restrict__ uh) {
    __shared__ float s_sh[272];            // [a*17 + c]
    __shared__ float o_sh[6144];           // [c*384 + o1l*16 + dd]
    const int b = blockIdx.x, og = blockIdx.y, tid = threadIdx.x;
    float acc = 0.f;
    #pragma unroll 8
    for (int s = 0; s < 48; ++s) acc += spart2[((size_t)s * 64 + b) * 256 + tid];
    s_sh[(tid >> 4) * 17 + (tid & 15)] = acc;
    for (int i = tid; i < 6144; i += 256) {
        const int c = i / 384, rem = i - c * 384;
        o_sh[i] = O[c * 1536 + og * 384 + rem];     // 384-float coalesced runs
    }
    __syncthreads();
    const int dd = tid >> 4, a = tid & 15;
    #pragma unroll
    for (int o1 = 0; o1 < 24; ++o1) {
        float u = 0.f;
        #pragma unroll
        for (int c = 0; c < 16; ++c) u += s_sh[a * 17 + c] * o_sh[c * 384 + o1 * 16 + dd];
        uh[((size_t)b * 96 + og * 24 + o1) * 256 + tid] = (f16)u;
    }
}

// ---- single-f16 MFMA GEMM, m97 structure (validated R6/R7/R8 body) ----
// 128x128 tile, BK=64, 4 waves (2x2), wave-tile 64x64, global_load_lds staging.
// LDS: [region 0..7][ks 0..1][lane 0..63][8 f16]; 32 KB -> 4 blocks/CU.
// EPI 0: Ch[bz][M][N] = (f16)v (split-K partial);
// EPI 1: +bias, relu -> Ch; EPI 2: +bias -> Cf (fp32).
template<int EPI>
__global__ __launch_bounds__(256, 4) void trgemm_kernel(
    const f16* __restrict__ Ah, const f16* __restrict__ BTh,
    const float* __restrict__ bias,
    float* __restrict__ Cf, f16* __restrict__ Ch,
    int M, int N, int K, int kchunk)
{
    __shared__ f16 As[8192];
    __shared__ f16 Bs[8192];
    const int n0 = blockIdx.x * 128, m0 = blockIdx.y * 128;
    const int kbase = blockIdx.z * kchunk;
    const int tid = threadIdx.x;
    const int w = tid >> 6, lane = tid & 63;
    const int wm = w >> 1, wn = w & 1;
    const int lr = lane & 15, lq = lane >> 4;

    // staging: wave w stages regions {2w, 2w+1} of both A and B
    const int ra = 2 * w;
    size_t aoff0 = (size_t)(m0 + ra * 16 + lr) * K + kbase + lq * 8;
    size_t aoff1 = aoff0 + (size_t)16 * K;
    size_t boff0 = (size_t)(n0 + ra * 16 + lr) * K + kbase + lq * 8;
    size_t boff1 = boff0 + (size_t)16 * K;

    f32x4 acc[4][4];
    #pragma unroll
    for (int i = 0; i < 4; ++i)
        #pragma unroll
        for (int j = 0; j < 4; ++j) acc[i][j] = (f32x4)0.f;

    const int nkt = kchunk >> 6;
    for (int kt = 0; kt < nkt; ++kt) {
        __syncthreads();   // all waves done reading previous tile
        #pragma unroll
        for (int c = 0; c < 2; ++c) {
            gload16(Ah + aoff0 + c * 32, &As[(ra + 0) * 1024 + c * 512]);
            gload16(Ah + aoff1 + c * 32, &As[(ra + 1) * 1024 + c * 512]);
            gload16(BTh + boff0 + c * 32, &Bs[(ra + 0) * 1024 + c * 512]);
            gload16(BTh + boff1 + c * 32, &Bs[(ra + 1) * 1024 + c * 512]);
        }
        aoff0 += 64; aoff1 += 64; boff0 += 64; boff1 += 64;
        __syncthreads();   // compiler drains vmcnt before barrier -> tile landed
        #pragma unroll
        for (int ks = 0; ks < 2; ++ks) {
            f16x8 afh[4], bfh[4];
            #pragma unroll
            for (int mf = 0; mf < 4; ++mf)
                afh[mf] = *(const f16x8*)&As[(wm * 4 + mf) * 1024 + ks * 512 + lane * 8];
            #pragma unroll
            for (int nf = 0; nf < 4; ++nf)
                bfh[nf] = *(const f16x8*)&Bs[(wn * 4 + nf) * 1024 + ks * 512 + lane * 8];
            #pragma unroll
            for (int mf = 0; mf < 4; ++mf)
                #pragma unroll
                for (int nf = 0; nf < 4; ++nf)
                    acc[mf][nf] = __builtin_amdgcn_mfma_f32_16x16x32_f16(afh[mf], bfh[nf], acc[mf][nf], 0, 0, 0);
        }
    }

    #pragma unroll
    for (int mf = 0; mf < 4; ++mf)
        #pragma unroll
        for (int nf = 0; nf < 4; ++nf)
            #pragma unroll
            for (int r = 0; r < 4; ++r) {
                const int row = m0 + wm * 64 + mf * 16 + lq * 4 + r;
                const int col = n0 + wn * 64 + nf * 16 + lr;
                float v = acc[mf][nf][r];
                if constexpr (EPI == 0) {
                    Ch[((size_t)blockIdx.z * M + row) * N + col] = (f16)v;
                } else {
                    v += bias[(size_t)(row % 96) * N + col];
                    if constexpr (EPI == 1) {
                        v = fmaxf(v, 0.f);
                        Ch[(size_t)row * N + col] = (f16)v;
                    } else {
                        Cf[(size_t)row * N + col] = v;
                    }
                }
            }
}

extern "C" void kernel_launch(void* const* d_in, const int* in_sizes, int n_in,
                              void* d_out, int out_size, void* d_ws, size_t ws_size,
                              hipStream_t stream) {
    const float* x        = (const float*)d_in[0];
    const float* c1_in2   = (const float*)d_in[1];
    const float* c1_in3   = (const float*)d_in[2];
    const float* c1_ind   = (const float*)d_in[3];
    const float* c1_oseq  = (const float*)d_in[4];
    const float* c1_off   = (const float*)d_in[5];
    const float* b1       = (const float*)d_in[6];
    const float* c2_iseq  = (const float*)d_in[7];
    const float* c2_iff   = (const float*)d_in[8];
    const float* c2_out2  = (const float*)d_in[9];
    const float* c2_out3  = (const float*)d_in[10];
    const float* c2_outd  = (const float*)d_in[11];
    const float* b2       = (const float*)d_in[12];
    float* out = (float*)d_out;

    // ---- workspace layout: byte-identical offsets to proven R7/R8 ----
    char* base = (char*)d_ws;
    float* Pseq1 = (float*)base;                       // 24576 f (P2 layout)
    float* Qseq2 = (float*)(base + 98304);             // 24576 f (old layout)
    f16*   BT1h  = (f16*)(base + 196608);              // 131072 (+dead l slot)
    f16*   BT2h  = BT1h + 2 * 131072;                  // 524288
    f16*   BT3h  = BT2h + 2 * 524288;                  // 524288
    f16*   BT4h  = BT3h + 2 * 524288;                  // 131072
    char*  hreg  = base + 5439488;                     // 50331648 B
    f16*   hh    = (f16*)hreg;                         // 12582912 f16 (25165824 B)
    f16*   xh    = (f16*)hreg;                         // alias (dies before h)
    float* spart2= (float*)(hreg + 25165824);          // 48*64*256 f = 3145728 B
    float* P2c   = (float*)(hreg + 28311552);          // 24576 f (repacked c2_iseq)
    char*  zreg  = base + 55771136;                    // 25165824 B
    f16*   zp    = (f16*)zreg;                         // SK=8 x 1572864 f16
    f16*   uh    = (f16*)zreg;                         // alias (zp dead at sexpand)

    const int SK = 8;

    // prep
    build_chain2_kernel<<<288, 256, 0, stream>>>(c1_in2, c1_in3, c2_out2, c2_out3,
                                                 c2_iseq, Pseq1, Qseq2, P2c);
    prep_bt_kernel<<<2720, 256, 0, stream>>>(c1_ind, c1_off, c2_iff, c2_outd,
                                             BT1h, BT2h, BT3h, BT4h);
    xsplit_kernel<<<3072, 256, 0, stream>>>(x, xh);

    // layer 1
    trgemm_kernel<0><<<dim3(2, 48, SK), 256, 0, stream>>>(xh, BT1h, nullptr,
                                                          nullptr, zp, 6144, 256, 512, 512 / SK);
    sfold_kernel<<<dim3(64, 6, SK), 256, 0, stream>>>(zp, Pseq1, spart2);
    sexpand_kernel<<<dim3(64, 4), 256, 0, stream>>>(spart2, c1_oseq, uh);
    trgemm_kernel<1><<<dim3(16, 48, 1), 256, 0, stream>>>(uh, BT2h, b1,
                                                          nullptr, hh, 6144, 2048, 256, 256);
    // layer 2
    trgemm_kernel<0><<<dim3(2, 48, SK), 256, 0, stream>>>(hh, BT3h, nullptr,
                                                          nullptr, zp, 6144, 256, 2048, 2048 / SK);
    sfold_kernel<<<dim3(64, 6, SK), 256, 0, stream>>>(zp, P2c, spart2);
    sexpand_kernel<<<dim3(64, 4), 256, 0, stream>>>(spart2, Qseq2, uh);
    trgemm_kernel<2><<<dim3(4, 48, 1), 256, 0, stream>>>(uh, BT4h, b2,
                                                         out, nullptr, 6144, 512, 256, 256);
}

// Round 10
// 229.675 us; speedup vs baseline: 1.0991x; 1.0014x over previous
//
#include <hip/hip_runtime.h>

// Tensor-ring FFN on MI355X — single-f16-product MFMA (fp32 acc).
// Round 10 = Round-9 (proven) with node-count reduction: ALL prep fused into
// one kernel (chain+repack+permM+tiled-permO+xsplit, 3680 blocks) -> 9 graph
// nodes total. permO now LDS-tiled (contiguous runs, padded stride). GEMM /
// fold / expand kernels and workspace offsets byte-identical to R9.

typedef _Float16 f16;
typedef f16 f16x8 __attribute__((ext_vector_type(8)));
typedef f16 f16x4 __attribute__((ext_vector_type(4)));
typedef float f32x4 __attribute__((ext_vector_type(4)));

__device__ __forceinline__ void gload16(const void* g, void* l) {
    __builtin_amdgcn_global_load_lds(
        (const __attribute__((address_space(1))) void*)g,
        (__attribute__((address_space(3))) void*)l, 16, 0, 0);
}

// ---------------- fused prep ----------------
// [0,192)    chain c=blk/96, l=blk%96: M(l)=G1..G5@C3
//            chain0 -> P2 layout P[l*256+r*16+rp]; chain1 -> Q[(rp*96+l)*16+r]
// [192,288)  repack c2_iseq -> P2c[l*256+r*16+rp]
// [288,320)  permM c1_ind  (K=512)  -> BT1h
// [320,448)  permM c2_iff  (K=2048) -> BT3h
// [448,576)  permO c1_off  (N=2048) -> BT2h   (tiled)
// [576,608)  permO c2_outd (N=512)  -> BT4h   (tiled)
// [608,3680) xsplit (3072 blocks)
__device__ __forceinline__ void chain_body(const float* __restrict__ a5, const float* __restrict__ a3,
                                           const float* __restrict__ b5, const float* __restrict__ b3,
                                           float* __restrict__ Pout, float* __restrict__ Qout,
                                           int blk, float* Ma, float* Mb) {
    const int l = blk % 96, chain = blk / 96;
    const float* G5 = chain ? b5 : a5;
    const float* G3 = chain ? b3 : a3;
    const int i6 = l % 3, lh = l / 3;
    const int dig[5] = {(lh >> 4) & 1, (lh >> 3) & 1, (lh >> 2) & 1, (lh >> 1) & 1, lh & 1};
    const int a = threadIdx.x >> 4, bn = threadIdx.x & 15;
    Ma[threadIdx.x] = G5[a * 32 + dig[0] * 16 + bn];
    __syncthreads();
    float* cur = Ma; float* nxt = Mb;
    for (int g = 1; g < 5; ++g) {
        float s = 0.f;
        #pragma unroll
        for (int r = 0; r < 16; ++r)
            s += cur[a * 16 + r] * G5[g * 512 + r * 32 + dig[g] * 16 + bn];
        nxt[threadIdx.x] = s;
        __syncthreads();
        float* t = cur; cur = nxt; nxt = t;
    }
    float s = 0.f;
    #pragma unroll
    for (int r = 0; r < 16; ++r)
        s += cur[a * 16 + r] * G3[r * 48 + i6 * 16 + bn];
    if (chain == 0) Pout[l * 256 + bn * 16 + a] = s;       // P2 layout
    else            Qout[(a * 96 + l) * 16 + bn] = s;      // old layout (O)
}
__device__ __forceinline__ void permM_body(const float* __restrict__ in, f16* __restrict__ bh,
                                           int K, int q, int k0, float* t) {
    const float* src = in + ((size_t)q * K + k0) * 16;
    for (int i = threadIdx.x; i < 1024; i += 256)
        ((float4*)t)[i] = ((const float4*)src)[i];       // t[k_local*16 + j]
    __syncthreads();
    const int j = threadIdx.x >> 4, kc = (threadIdx.x & 15) * 16;
    f16* dh = bh + (size_t)(q * 16 + j) * K + k0 + kc;
    f16 vh[16];
    #pragma unroll
    for (int i = 0; i < 16; ++i) vh[i] = (f16)t[(kc + i) * 16 + j];
    *(f16x8*)(dh) = *(f16x8*)&vh[0]; *(f16x8*)(dh + 8) = *(f16x8*)&vh[8];
}
// tiled permO: BT[n*256+k] = in[((k>>4)*N + n)*16 + (k&15)], 16 n per block
__device__ __forceinline__ void permO_body(const float* __restrict__ in, f16* __restrict__ bh,
                                           int N, int blk, float* t) {
    const int n0 = blk * 16;
    for (int i = threadIdx.x; i < 4096; i += 256) {
        const int kq = i >> 8, rem = i & 255;
        t[kq * 257 + rem] = in[(size_t)kq * N * 16 + n0 * 16 + rem];   // contiguous runs
    }
    __syncthreads();
    const int nl = threadIdx.x >> 4, kq = threadIdx.x & 15;
    f16 vh[16];
    #pragma unroll
    for (int i = 0; i < 16; ++i) vh[i] = (f16)t[kq * 257 + nl * 16 + i];
    f16* dh = bh + (size_t)(n0 + nl) * 256 + kq * 16;
    *(f16x8*)(dh) = *(f16x8*)&vh[0]; *(f16x8*)(dh + 8) = *(f16x8*)&vh[8];
}
__global__ void prep_all_kernel(
    const float* __restrict__ c1_in2, const float* __restrict__ c1_in3,
    const float* __restrict__ c2_out2, const float* __restrict__ c2_out3,
    const float* __restrict__ c2_iseq,
    float* Pseq1, float* Qseq2, float* P2c,
    const float* __restrict__ c1_ind, const float* __restrict__ c1_off,
    const float* __restrict__ c2_iff, const float* __restrict__ c2_outd,
    f16* BT1h, f16* BT2h, f16* BT3h, f16* BT4h,
    const float* __restrict__ x, f16* __restrict__ xh)
{
    __shared__ float t[4608];
    int b = blockIdx.x;
    if (b < 192) { chain_body(c1_in2, c1_in3, c2_out2, c2_out3, Pseq1, Qseq2, b, t, t + 256); return; }
    if (b < 288) {   // repack c2_iseq into P2 layout
        const int l = b - 192;
        const int a = threadIdx.x >> 4, bn = threadIdx.x & 15;
        P2c[l * 256 + bn * 16 + a] = c2_iseq[(a * 96 + l) * 16 + bn];
        return;
    }
    b -= 288;
    if (b < 32)   { permM_body(c1_ind, BT1h, 512,  b & 15, (b >> 4) * 256, t); return; }
    b -= 32;
    if (b < 128)  { permM_body(c2_iff, BT3h, 2048, b & 15, (b >> 4) * 256, t); return; }
    b -= 128;
    if (b < 128)  { permO_body(c1_off, BT2h, 2048, b, t); return; }
    b -= 128;
    if (b < 32)   { permO_body(c2_outd, BT4h, 512, b, t); return; }
    b -= 32;
    {   // xsplit, 3072 blocks
        const int idx = b * 256 + threadIdx.x;
        const float4 v = ((const float4*)x)[idx];
        f16x4 hh;
        hh[0] = (f16)v.x; hh[1] = (f16)v.y; hh[2] = (f16)v.z; hh[3] = (f16)v.w;
        ((f16x4*)xh)[idx] = hh;
    }
}

// ---- ring fold, one sk-slice per block: grid (64 b, 6 lc, SK sk) ----
__global__ void sfold_kernel(const f16* __restrict__ z, const float* __restrict__ P2,
                             float* __restrict__ spart2) {
    __shared__ f16 zs[4096];     // [l16][256] f16 (8 KB)
    __shared__ float Ps[4096];   // [(l*16+r)*16 + rp] (16 KB)
    const int b = blockIdx.x, lc = blockIdx.y, sk = blockIdx.z, tid = threadIdx.x;
    const int r0 = tid >> 4, rE = tid & 15;
    const float4* psrc = (const float4*)(P2 + lc * 4096);
    for (int i = tid; i < 1024; i += 256) ((float4*)Ps)[i] = psrc[i];   // coalesced
    const f16x8* zsrc = (const f16x8*)(z + ((size_t)sk * 6144 + b * 96 + lc * 16) * 256);
    for (int i = tid; i < 512; i += 256) ((f16x8*)zs)[i] = zsrc[i];
    __syncthreads();
    float acc = 0.f;
    #pragma unroll
    for (int l = 0; l < 16; ++l)
        #pragma unroll
        for (int r = 0; r < 16; ++r)
            acc += (float)zs[l * 256 + r * 16 + rE] * Ps[(l * 16 + r) * 16 + r0];
    spart2[(((size_t)sk * 6 + lc) * 64 + b) * 256 + tid] = acc;
}

// ---- fused reduce+expand: grid (64 b, 4 og), 24 o1 per block ----
__global__ void sexpand_kernel(const float* __restrict__ spart2, const float* __restrict__ O,
                               f16* __restrict__ uh) {
    __shared__ float s_sh[272];            // [a*17 + c]
    __shared__ float o_sh[6144];           // [c*384 + o1l*16 + dd]
    const int b = blockIdx.x, og = blockIdx.y, tid = threadIdx.x;
    float acc = 0.f;
    #pragma unroll 8
    for (int s = 0; s < 48; ++s) acc += spart2[((size_t)s * 64 + b) * 256 + tid];
    s_sh[(tid >> 4) * 17 + (tid & 15)] = acc;
    for (int i = tid; i < 6144; i += 256) {
        const int c = i / 384, rem = i - c * 384;
        o_sh[i] = O[c * 1536 + og * 384 + rem];     // 384-float coalesced runs
    }
    __syncthreads();
    const int dd = tid >> 4, a = tid & 15;
    #pragma unroll
    for (int o1 = 0; o1 < 24; ++o1) {
        float u = 0.f;
        #pragma unroll
        for (int c = 0; c < 16; ++c) u += s_sh[a * 17 + c] * o_sh[c * 384 + o1 * 16 + dd];
        uh[((size_t)b * 96 + og * 24 + o1) * 256 + tid] = (f16)u;
    }
}

// ---- single-f16 MFMA GEMM, m97 structure (validated R6-R9 body) ----
// 128x128 tile, BK=64, 4 waves (2x2), wave-tile 64x64, global_load_lds staging.
// LDS: [region 0..7][ks 0..1][lane 0..63][8 f16]; 32 KB -> 4 blocks/CU.
// EPI 0: Ch[bz][M][N] = (f16)v (split-K partial);
// EPI 1: +bias, relu -> Ch; EPI 2: +bias -> Cf (fp32).
template<int EPI>
__global__ __launch_bounds__(256, 4) void trgemm_kernel(
    const f16* __restrict__ Ah, const f16* __restrict__ BTh,
    const float* __restrict__ bias,
    float* __restrict__ Cf, f16* __restrict__ Ch,
    int M, int N, int K, int kchunk)
{
    __shared__ f16 As[8192];
    __shared__ f16 Bs[8192];
    const int n0 = blockIdx.x * 128, m0 = blockIdx.y * 128;
    const int kbase = blockIdx.z * kchunk;
    const int tid = threadIdx.x;
    const int w = tid >> 6, lane = tid & 63;
    const int wm = w >> 1, wn = w & 1;
    const int lr = lane & 15, lq = lane >> 4;

    // staging: wave w stages regions {2w, 2w+1} of both A and B
    const int ra = 2 * w;
    size_t aoff0 = (size_t)(m0 + ra * 16 + lr) * K + kbase + lq * 8;
    size_t aoff1 = aoff0 + (size_t)16 * K;
    size_t boff0 = (size_t)(n0 + ra * 16 + lr) * K + kbase + lq * 8;
    size_t boff1 = boff0 + (size_t)16 * K;

    f32x4 acc[4][4];
    #pragma unroll
    for (int i = 0; i < 4; ++i)
        #pragma unroll
        for (int j = 0; j < 4; ++j) acc[i][j] = (f32x4)0.f;

    const int nkt = kchunk >> 6;
    for (int kt = 0; kt < nkt; ++kt) {
        __syncthreads();   // all waves done reading previous tile
        #pragma unroll
        for (int c = 0; c < 2; ++c) {
            gload16(Ah + aoff0 + c * 32, &As[(ra + 0) * 1024 + c * 512]);
            gload16(Ah + aoff1 + c * 32, &As[(ra + 1) * 1024 + c * 512]);
            gload16(BTh + boff0 + c * 32, &Bs[(ra + 0) * 1024 + c * 512]);
            gload16(BTh + boff1 + c * 32, &Bs[(ra + 1) * 1024 + c * 512]);
        }
        aoff0 += 64; aoff1 += 64; boff0 += 64; boff1 += 64;
        __syncthreads();   // compiler drains vmcnt before barrier -> tile landed
        #pragma unroll
        for (int ks = 0; ks < 2; ++ks) {
            f16x8 afh[4], bfh[4];
            #pragma unroll
            for (int mf = 0; mf < 4; ++mf)
                afh[mf] = *(const f16x8*)&As[(wm * 4 + mf) * 1024 + ks * 512 + lane * 8];
            #pragma unroll
            for (int nf = 0; nf < 4; ++nf)
                bfh[nf] = *(const f16x8*)&Bs[(wn * 4 + nf) * 1024 + ks * 512 + lane * 8];
            #pragma unroll
            for (int mf = 0; mf < 4; ++mf)
                #pragma unroll
                for (int nf = 0; nf < 4; ++nf)
                    acc[mf][nf] = __builtin_amdgcn_mfma_f32_16x16x32_f16(afh[mf], bfh[nf], acc[mf][nf], 0, 0, 0);
        }
    }

    #pragma unroll
    for (int mf = 0; mf < 4; ++mf)
        #pragma unroll
        for (int nf = 0; nf < 4; ++nf)
            #pragma unroll
            for (int r = 0; r < 4; ++r) {
                const int row = m0 + wm * 64 + mf * 16 + lq * 4 + r;
                const int col = n0 + wn * 64 + nf * 16 + lr;
                float v = acc[mf][nf][r];
                if constexpr (EPI == 0) {
                    Ch[((size_t)blockIdx.z * M + row) * N + col] = (f16)v;
                } else {
                    v += bias[(size_t)(row % 96) * N + col];
                    if constexpr (EPI == 1) {
                        v = fmaxf(v, 0.f);
                        Ch[(size_t)row * N + col] = (f16)v;
                    } else {
                        Cf[(size_t)row * N + col] = v;
                    }
                }
            }
}

extern "C" void kernel_launch(void* const* d_in, const int* in_sizes, int n_in,
                              void* d_out, int out_size, void* d_ws, size_t ws_size,
                              hipStream_t stream) {
    const float* x        = (const float*)d_in[0];
    const float* c1_in2   = (const float*)d_in[1];
    const float* c1_in3   = (const float*)d_in[2];
    const float* c1_ind   = (const float*)d_in[3];
    const float* c1_oseq  = (const float*)d_in[4];
    const float* c1_off   = (const float*)d_in[5];
    const float* b1       = (const float*)d_in[6];
    const float* c2_iseq  = (const float*)d_in[7];
    const float* c2_iff   = (const float*)d_in[8];
    const float* c2_out2  = (const float*)d_in[9];
    const float* c2_out3  = (const float*)d_in[10];
    const float* c2_outd  = (const float*)d_in[11];
    const float* b2       = (const float*)d_in[12];
    float* out = (float*)d_out;

    // ---- workspace layout: byte-identical offsets to proven R7-R9 ----
    char* base = (char*)d_ws;
    float* Pseq1 = (float*)base;                       // 24576 f (P2 layout)
    float* Qseq2 = (float*)(base + 98304);             // 24576 f (old layout)
    f16*   BT1h  = (f16*)(base + 196608);              // 131072 (+dead l slot)
    f16*   BT2h  = BT1h + 2 * 131072;                  // 524288
    f16*   BT3h  = BT2h + 2 * 524288;                  // 524288
    f16*   BT4h  = BT3h + 2 * 524288;                  // 131072
    char*  hreg  = base + 5439488;                     // 50331648 B
    f16*   hh    = (f16*)hreg;                         // 12582912 f16 (25165824 B)
    f16*   xh    = (f16*)hreg;                         // alias (dies before h)
    float* spart2= (float*)(hreg + 25165824);          // 48*64*256 f = 3145728 B
    float* P2c   = (float*)(hreg + 28311552);          // 24576 f (repacked c2_iseq)
    char*  zreg  = base + 55771136;                    // 25165824 B
    f16*   zp    = (f16*)zreg;                         // SK=8 x 1572864 f16
    f16*   uh    = (f16*)zreg;                         // alias (zp dead at sexpand)

    const int SK = 8;

    // fused prep: chain(192)+repack(96)+permM(160)+permO(160)+xsplit(3072)
    prep_all_kernel<<<3680, 256, 0, stream>>>(c1_in2, c1_in3, c2_out2, c2_out3, c2_iseq,
                                              Pseq1, Qseq2, P2c,
                                              c1_ind, c1_off, c2_iff, c2_outd,
                                              BT1h, BT2h, BT3h, BT4h, x, xh);

    // layer 1
    trgemm_kernel<0><<<dim3(2, 48, SK), 256, 0, stream>>>(xh, BT1h, nullptr,
                                                          nullptr, zp, 6144, 256, 512, 512 / SK);
    sfold_kernel<<<dim3(64, 6, SK), 256, 0, stream>>>(zp, Pseq1, spart2);
    sexpand_kernel<<<dim3(64, 4), 256, 0, stream>>>(spart2, c1_oseq, uh);
    trgemm_kernel<1><<<dim3(16, 48, 1), 256, 0, stream>>>(uh, BT2h, b1,
                                                          nullptr, hh, 6144, 2048, 256, 256);
    // layer 2
    trgemm_kernel<0><<<dim3(2, 48, SK), 256, 0, stream>>>(hh, BT3h, nullptr,
                                                          nullptr, zp, 6144, 256, 2048, 2048 / SK);
    sfold_kernel<<<dim3(64, 6, SK), 256, 0, stream>>>(zp, P2c, spart2);
    sexpand_kernel<<<dim3(64, 4), 256, 0, stream>>>(spart2, Qseq2, uh);
    trgemm_kernel<2><<<dim3(4, 48, 1), 256, 0, stream>>>(uh, BT4h, b2,
                                                         out, nullptr, 6144, 512, 256, 256);
}